// Round 1
// baseline (783.043 us; speedup 1.0000x reference)
//
#include <hip/hip_runtime.h>

#define N_NODES 50000
#define N_EDGES 600000
#define HDIM 128
#define KEIG 32
#define FEAT9 1152  // 9*H

typedef short s8v __attribute__((ext_vector_type(8)));
typedef __bf16 bf8v __attribute__((ext_vector_type(8)));
typedef float f4v __attribute__((ext_vector_type(4)));

__device__ __forceinline__ unsigned short f2bf(float f) {
    unsigned u = __float_as_uint(f);
    u += 0x7fff + ((u >> 16) & 1);   // round to nearest even
    return (unsigned short)(u >> 16);
}
__device__ __forceinline__ float bf2f(unsigned short h) {
    return __uint_as_float(((unsigned)h) << 16);
}
__device__ __forceinline__ bf8v as_bf(s8v v) { return __builtin_bit_cast(bf8v, v); }

// ---------------- W pre-swizzle into MFMA B-fragment order -------------------
// B-frag (16x16x32 bf16): lane holds B[k = (lane>>4)*8 + j][n = lane&15], j=0..7
// layout: [kstep][ntile][lane][j] contiguous -> every load is 16B/lane coalesced
__global__ void k_prep(const float* __restrict__ Wp, const float* __restrict__ Wl,
                       unsigned short* __restrict__ Wswz,
                       unsigned short* __restrict__ WlA,
                       unsigned short* __restrict__ WlB) {
    int tid = blockIdx.x * blockDim.x + threadIdx.x;
    if (tid < 36 * 8 * 64 * 8) {
        int j = tid & 7, lane = (tid >> 3) & 63, tn = (tid >> 9) & 7, s = tid >> 12;
        int k = s * 32 + (lane >> 4) * 8 + j;
        int c = tn * 16 + (lane & 15);
        Wswz[tid] = f2bf(Wp[k * HDIM + c]);
    } else {
        int t2 = tid - 36 * 8 * 64 * 8;
        if (t2 < 4 * 8 * 64 * 8) {
            int j = t2 & 7, lane = (t2 >> 3) & 63, tn = (t2 >> 9) & 7, s = t2 >> 12;
            int k = s * 32 + (lane >> 4) * 8 + j;
            int c = tn * 16 + (lane & 15);
            WlA[t2] = f2bf(Wl[k * HDIM + c]);
            WlB[t2] = f2bf(Wl[(128 + k) * HDIM + c]);
        }
    }
}

// ---------------- coeff[k,h] = sum_n eig[n,k] * deg[n] * x[n,h] --------------
__global__ void k_coeff(const float* __restrict__ node_fts, const float* __restrict__ deg,
                        const float* __restrict__ eig, float* __restrict__ coeff) {
    int h = threadIdx.x;              // 128
    int base = blockIdx.x * 250;      // 200 blocks * 250 rows = 50000
    float acc[KEIG];
#pragma unroll
    for (int k = 0; k < KEIG; k++) acc[k] = 0.f;
    for (int r = 0; r < 250; r++) {
        int n = base + r;
        float v = deg[n] * node_fts[n * HDIM + h];
        const float4* e4 = (const float4*)(eig + n * KEIG);
#pragma unroll
        for (int q = 0; q < 8; q++) {
            float4 e = e4[q];
            acc[q * 4 + 0] += e.x * v;
            acc[q * 4 + 1] += e.y * v;
            acc[q * 4 + 2] += e.z * v;
            acc[q * 4 + 3] += e.w * v;
        }
    }
#pragma unroll
    for (int k = 0; k < KEIG; k++) atomicAdd(&coeff[k * HDIM + h], acc[k]);
}

// coeff2 = coeff * exp(-lambda_k * softplus(t_h))
__global__ void k_scale(const float* __restrict__ coeff, const float* __restrict__ lam,
                        const float* __restrict__ dt, float* __restrict__ coeff2) {
    int i = blockIdx.x * blockDim.x + threadIdx.x;  // 4096
    int k = i >> 7, h = i & 127;
    float t = log1pf(expf(dt[h]));
    coeff2[i] = coeff[i] * expf(-lam[k] * t);
}

// x[n,h] = sum_k eig[n,k] * coeff2[k,h]  -> feats[:, 0:128] (bf16)
__global__ void k_diffuse(const float* __restrict__ eig, const float* __restrict__ coeff2,
                          unsigned short* __restrict__ feats) {
    __shared__ float c2[KEIG * HDIM];
    int h = threadIdx.x;  // 128
    for (int j = 0; j < KEIG; j++) c2[j * HDIM + h] = coeff2[j * HDIM + h];
    __syncthreads();
    int base = blockIdx.x * 64;
    for (int r = 0; r < 64; r++) {
        int n = base + r;
        if (n >= N_NODES) break;
        const float4* e4 = (const float4*)(eig + n * KEIG);
        float s = 0.f;
#pragma unroll
        for (int q = 0; q < 8; q++) {
            float4 e = e4[q];
            s += e.x * c2[(q * 4 + 0) * HDIM + h] + e.y * c2[(q * 4 + 1) * HDIM + h]
               + e.z * c2[(q * 4 + 2) * HDIM + h] + e.w * c2[(q * 4 + 3) * HDIM + h];
        }
        feats[(size_t)n * FEAT9 + h] = f2bf(s);
    }
}

// ---------------- CSR build ----------------
__global__ void k_hist(const int* __restrict__ dst, int* __restrict__ cnt) {
    int e = blockIdx.x * blockDim.x + threadIdx.x;
    if (e < N_EDGES) atomicAdd(&cnt[dst[e]], 1);
}

__global__ void k_scan_part(const int* __restrict__ cnt, int* __restrict__ bsum) {
    __shared__ int sm[256];
    int t = threadIdx.x, b = blockIdx.x;
    int base = b * 1024 + t * 4;
    int s = 0;
#pragma unroll
    for (int j = 0; j < 4; j++) { int i = base + j; if (i < N_NODES) s += cnt[i]; }
    sm[t] = s;
    __syncthreads();
    for (int d = 128; d > 0; d >>= 1) {
        if (t < d) sm[t] += sm[t + d];
        __syncthreads();
    }
    if (t == 0) bsum[b] = sm[0];
}

__global__ void k_scan_mid(const int* __restrict__ bsum, int* __restrict__ boff) {
    int t = threadIdx.x;  // 64
    int v = (t < 50) ? bsum[t] : 0;
    int x = v;
#pragma unroll
    for (int d = 1; d < 64; d <<= 1) {
        int y = __shfl_up(x, d, 64);
        if (t >= d) x += y;
    }
    boff[t] = x - v;  // exclusive
}

__global__ void k_scan_out(const int* __restrict__ cnt, const int* __restrict__ boff,
                           int* __restrict__ offsets, int* __restrict__ cursor) {
    __shared__ int sm[256];
    int t = threadIdx.x, b = blockIdx.x;
    int base = b * 1024 + t * 4;
    int c[4]; int ts = 0;
#pragma unroll
    for (int j = 0; j < 4; j++) { int i = base + j; c[j] = (i < N_NODES) ? cnt[i] : 0; ts += c[j]; }
    sm[t] = ts;
    __syncthreads();
    for (int d = 1; d < 256; d <<= 1) {
        int add = (t >= d) ? sm[t - d] : 0;
        __syncthreads();
        sm[t] += add;
        __syncthreads();
    }
    int run = boff[b] + sm[t] - ts;  // exclusive within-chip
#pragma unroll
    for (int j = 0; j < 4; j++) {
        int i = base + j;
        if (i < N_NODES) { offsets[i] = run; cursor[i] = run; run += c[j]; }
    }
    if (b == 0 && t == 0) offsets[N_NODES] = N_EDGES;
}

__global__ void k_bucket(const int* __restrict__ ei, const float* __restrict__ F,
                         int* __restrict__ cursor, int* __restrict__ ssrc,
                         float* __restrict__ sF) {
    int e = blockIdx.x * blockDim.x + threadIdx.x;
    if (e < N_EDGES) {
        int d = ei[N_EDGES + e];
        int p = atomicAdd(&cursor[d], 1);
        ssrc[p] = ei[e];
        sF[p] = F[e];
    }
}

// ---------------- per-node aggregation -> feats[:, 128:1152] ----------------
__global__ void k_agg(unsigned short* __restrict__ feats, const int* __restrict__ offsets,
                      const int* __restrict__ ssrc, const float* __restrict__ sF,
                      const float* __restrict__ degv, const float* __restrict__ Fdig) {
    int n = blockIdx.x;
    int h = threadIdx.x;  // 128
    int beg = offsets[n], end = offsets[n + 1];
    float sum = 0.f, mx = -3.4e38f, wsum = 0.f, fsum = 0.f, wS = 0.f;
    for (int e = beg; e < end; e++) {
        int s = ssrc[e];
        float F = sF[e];
        float w = fabsf(F);
        float m = bf2f(feats[(size_t)s * FEAT9 + h]);
        sum += m;
        mx = fmaxf(mx, m);
        wsum += w * m;
        fsum += F * m;
        wS += w;
    }
    float dv = degv[n];
    float mean = sum / dv;
    float maxv = (end > beg) ? mx : 0.f;
    float dav = wsum / (wS + 1e-8f);
    float xn = bf2f(feats[(size_t)n * FEAT9 + h]);
    float ddx = fsum - Fdig[n] * xn;
    float amp = log1pf(dv) / 2.5649493574615367f;  // log(13)
    unsigned short* fr = feats + (size_t)n * FEAT9 + h;
    fr[128]  = f2bf(mean);
    fr[256]  = f2bf(maxv);
    fr[384]  = f2bf(dav);
    fr[512]  = f2bf(ddx);
    fr[640]  = f2bf(mean * amp);
    fr[768]  = f2bf(maxv * amp);
    fr[896]  = f2bf(dav * amp);
    fr[1024] = f2bf(ddx * amp);
}

// ---------------- fused MFMA GEMM: h=relu(feats@Wp+bp)*norm; out=x@WlA+h@WlB+bl+res
__global__ __launch_bounds__(256) void k_gemm(
    const unsigned short* __restrict__ feats, const unsigned short* __restrict__ Wswz,
    const unsigned short* __restrict__ WlA, const unsigned short* __restrict__ WlB,
    const float* __restrict__ b_post, const float* __restrict__ b_last,
    const float* __restrict__ norm_n, const float* __restrict__ node_fts,
    float* __restrict__ out) {
    __shared__ unsigned short As[64 * 40];  // 64 rows x 32k, +8 pad (2-way banks)
    int tid = threadIdx.x;
    int wave = tid >> 6, lane = tid & 63;
    int m16 = lane & 15, quad = lane >> 4;
    int r0 = blockIdx.x * 64;

    // A staging map: thread -> (row, 16B chunk)
    int arow = tid >> 2, ac = tid & 3;
    int grow_st = r0 + arow;
    if (grow_st > N_NODES - 1) grow_st = N_NODES - 1;
    const unsigned short* gA = feats + (size_t)grow_st * FEAT9 + ac * 8;
    unsigned short* sA = As + arow * 40 + ac * 8;
    const unsigned short* aAddr = As + (wave * 16 + m16) * 40 + quad * 8;

    f4v acc1[8];
#pragma unroll
    for (int t = 0; t < 8; t++) acc1[t] = (f4v)(0.f);

    // GEMM1: feats[64 x 1152] @ W_post -> acc1 (h pre-activation)
    for (int s = 0; s < 36; s++) {
        __syncthreads();
        *(s8v*)sA = *(const s8v*)(gA + s * 32);
        __syncthreads();
        s8v a = *(const s8v*)aAddr;
        const s8v* bp = (const s8v*)Wswz + (size_t)(s * 8) * 64 + lane;
#pragma unroll
        for (int nt = 0; nt < 8; nt++) {
            s8v b = bp[nt * 64];
            acc1[nt] = __builtin_amdgcn_mfma_f32_16x16x32_bf16(as_bf(a), as_bf(b), acc1[nt], 0, 0, 0);
        }
    }

    // epilogue1: h = relu(acc1 + b_post[col]) * norm_n[row]   (in-place)
    int browbase = r0 + wave * 16 + quad * 4;
    float nrm[4];
#pragma unroll
    for (int r = 0; r < 4; r++) {
        int gr = browbase + r;
        if (gr > N_NODES - 1) gr = N_NODES - 1;
        nrm[r] = norm_n[gr];
    }
#pragma unroll
    for (int nt = 0; nt < 8; nt++) {
        float bb = b_post[nt * 16 + m16];
#pragma unroll
        for (int r = 0; r < 4; r++) {
            float v = acc1[nt][r] + bb;
            v = v > 0.f ? v : 0.f;
            acc1[nt][r] = v * nrm[r];
        }
    }

    f4v acc2[8];
#pragma unroll
    for (int t = 0; t < 8; t++) acc2[t] = (f4v)(0.f);

    // GEMM2a: x (feats cols 0..127) @ W_last[0:128]
    for (int s = 0; s < 4; s++) {
        __syncthreads();
        *(s8v*)sA = *(const s8v*)(gA + s * 32);
        __syncthreads();
        s8v a = *(const s8v*)aAddr;
        const s8v* bp = (const s8v*)WlA + (size_t)(s * 8) * 64 + lane;
#pragma unroll
        for (int nt = 0; nt < 8; nt++) {
            s8v b = bp[nt * 64];
            acc2[nt] = __builtin_amdgcn_mfma_f32_16x16x32_bf16(as_bf(a), as_bf(b), acc2[nt], 0, 0, 0);
        }
    }

    // GEMM2b: h @ W_last[128:256], h staged 32 cols at a time from registers
    for (int s = 0; s < 4; s++) {
        __syncthreads();
#pragma unroll
        for (int half = 0; half < 2; half++) {
            int nt = s * 2 + half;
#pragma unroll
            for (int r = 0; r < 4; r++) {
                As[(wave * 16 + quad * 4 + r) * 40 + half * 16 + m16] = f2bf(acc1[nt][r]);
            }
        }
        __syncthreads();
        s8v a = *(const s8v*)aAddr;
        const s8v* bp = (const s8v*)WlB + (size_t)(s * 8) * 64 + lane;
#pragma unroll
        for (int nt = 0; nt < 8; nt++) {
            s8v b = bp[nt * 64];
            acc2[nt] = __builtin_amdgcn_mfma_f32_16x16x32_bf16(as_bf(a), as_bf(b), acc2[nt], 0, 0, 0);
        }
    }

    // epilogue2: out = acc2 + b_last + node_fts
#pragma unroll
    for (int nt = 0; nt < 8; nt++) {
        int col = nt * 16 + m16;
        float bl = b_last[col];
#pragma unroll
        for (int r = 0; r < 4; r++) {
            int gr = browbase + r;
            if (gr < N_NODES) {
                out[(size_t)gr * HDIM + col] = acc2[nt][r] + bl + node_fts[(size_t)gr * HDIM + col];
            }
        }
    }
}

extern "C" void kernel_launch(void* const* d_in, const int* in_sizes, int n_in,
                              void* d_out, int out_size, void* d_ws, size_t ws_size,
                              hipStream_t stream) {
    const float* node_fts = (const float*)d_in[0];
    const int*   eidx     = (const int*)d_in[2];
    const float* Fnorm    = (const float*)d_in[3];
    const float* Fdig     = (const float*)d_in[4];
    const float* degv     = (const float*)d_in[5];
    const float* lam      = (const float*)d_in[8];
    const float* eig      = (const float*)d_in[9];
    const float* norm_n   = (const float*)d_in[11];
    const float* dtimes   = (const float*)d_in[13];
    const float* Wp       = (const float*)d_in[14];
    const float* bp       = (const float*)d_in[15];
    const float* Wl       = (const float*)d_in[16];
    const float* bl       = (const float*)d_in[17];
    float* out = (float*)d_out;

    char* w = (char*)d_ws;
    size_t off = 0;
    auto carve = [&](size_t bytes) -> char* {
        char* p = w + off;
        off = (off + bytes + 255) & ~(size_t)255;
        return p;
    };
    unsigned short* feats = (unsigned short*)carve((size_t)N_NODES * FEAT9 * 2);
    unsigned short* Wswz  = (unsigned short*)carve((size_t)36 * 8 * 64 * 8 * 2);
    unsigned short* WlA   = (unsigned short*)carve((size_t)4 * 8 * 64 * 8 * 2);
    unsigned short* WlB   = (unsigned short*)carve((size_t)4 * 8 * 64 * 8 * 2);
    float* coeff  = (float*)carve(KEIG * HDIM * 4);
    float* coeff2 = (float*)carve(KEIG * HDIM * 4);
    int* cnt      = (int*)carve((size_t)N_NODES * 4);
    int* offsets  = (int*)carve(((size_t)N_NODES + 1) * 4);
    int* cursor   = (int*)carve((size_t)N_NODES * 4);
    int* ssrc     = (int*)carve((size_t)N_EDGES * 4);
    float* sF     = (float*)carve((size_t)N_EDGES * 4);
    int* bsum     = (int*)carve(64 * 4);
    int* boff     = (int*)carve(64 * 4);

    hipMemsetAsync(coeff, 0, KEIG * HDIM * 4, stream);
    hipMemsetAsync(cnt, 0, (size_t)N_NODES * 4, stream);

    k_prep<<<640, 256, 0, stream>>>(Wp, Wl, Wswz, WlA, WlB);
    k_coeff<<<200, 128, 0, stream>>>(node_fts, degv, eig, coeff);
    k_scale<<<16, 256, 0, stream>>>(coeff, lam, dtimes, coeff2);
    k_diffuse<<<(N_NODES + 63) / 64, 128, 0, stream>>>(eig, coeff2, feats);
    k_hist<<<(N_EDGES + 255) / 256, 256, 0, stream>>>(eidx + N_EDGES, cnt);
    k_scan_part<<<50, 256, 0, stream>>>(cnt, bsum);
    k_scan_mid<<<1, 64, 0, stream>>>(bsum, boff);
    k_scan_out<<<50, 256, 0, stream>>>(cnt, boff, offsets, cursor);
    k_bucket<<<(N_EDGES + 255) / 256, 256, 0, stream>>>(eidx, Fnorm, cursor, ssrc, sF);
    k_agg<<<N_NODES, 128, 0, stream>>>(feats, offsets, ssrc, sF, degv, Fdig);
    k_gemm<<<(N_NODES + 63) / 64, 256, 0, stream>>>(feats, Wswz, WlA, WlB, bp, bl, norm_n,
                                                    node_fts, out);
}

// Round 2
// 652.334 us; speedup vs baseline: 1.2004x; 1.2004x over previous
//
#include <hip/hip_runtime.h>

#define N_NODES 50000
#define N_EDGES 600000
#define HDIM 128
#define KEIG 32
#define FEAT9 1152  // 9*H

typedef short s8v __attribute__((ext_vector_type(8)));
typedef __bf16 bf8v __attribute__((ext_vector_type(8)));
typedef float f4v __attribute__((ext_vector_type(4)));

__device__ __forceinline__ unsigned short f2bf(float f) {
    unsigned u = __float_as_uint(f);
    u += 0x7fff + ((u >> 16) & 1);   // round to nearest even
    return (unsigned short)(u >> 16);
}
__device__ __forceinline__ float bf2f(unsigned short h) {
    return __uint_as_float(((unsigned)h) << 16);
}
__device__ __forceinline__ unsigned pack2(float a, float b) {
    return (unsigned)f2bf(a) | ((unsigned)f2bf(b) << 16);
}
__device__ __forceinline__ bf8v as_bf(s8v v) { return __builtin_bit_cast(bf8v, v); }

// ---------------- W pre-swizzle into MFMA B-fragment order -------------------
// B-frag (16x16x32 bf16): lane holds B[k = (lane>>4)*8 + j][n = lane&15], j=0..7
// layout: [kstep][ntile][lane][j] contiguous -> every load is 16B/lane coalesced
__global__ void k_prep(const float* __restrict__ Wp, const float* __restrict__ Wl,
                       unsigned short* __restrict__ Wswz,
                       unsigned short* __restrict__ WlA,
                       unsigned short* __restrict__ WlB) {
    int tid = blockIdx.x * blockDim.x + threadIdx.x;
    if (tid < 36 * 8 * 64 * 8) {
        int j = tid & 7, lane = (tid >> 3) & 63, tn = (tid >> 9) & 7, s = tid >> 12;
        int k = s * 32 + (lane >> 4) * 8 + j;
        int c = tn * 16 + (lane & 15);
        Wswz[tid] = f2bf(Wp[k * HDIM + c]);
    } else {
        int t2 = tid - 36 * 8 * 64 * 8;
        if (t2 < 4 * 8 * 64 * 8) {
            int j = t2 & 7, lane = (t2 >> 3) & 63, tn = (t2 >> 9) & 7, s = t2 >> 12;
            int k = s * 32 + (lane >> 4) * 8 + j;
            int c = tn * 16 + (lane & 15);
            WlA[t2] = f2bf(Wl[k * HDIM + c]);
            WlB[t2] = f2bf(Wl[(128 + k) * HDIM + c]);
        }
    }
}

// ---------------- coeff[k,h] = sum_n eig[n,k] * deg[n] * x[n,h] --------------
// 1563 blocks x 32 rows (was 200 x 250 -> parallelism-starved)
__global__ void k_coeff(const float* __restrict__ node_fts, const float* __restrict__ deg,
                        const float* __restrict__ eig, float* __restrict__ coeff) {
    int h = threadIdx.x;              // 128
    int base = blockIdx.x * 32;
    int lim = N_NODES - base; if (lim > 32) lim = 32;
    float acc[KEIG];
#pragma unroll
    for (int k = 0; k < KEIG; k++) acc[k] = 0.f;
    for (int r = 0; r < lim; r++) {
        int n = base + r;
        float v = deg[n] * node_fts[n * HDIM + h];
        const float4* e4 = (const float4*)(eig + n * KEIG);
#pragma unroll
        for (int q = 0; q < 8; q++) {
            float4 e = e4[q];
            acc[q * 4 + 0] += e.x * v;
            acc[q * 4 + 1] += e.y * v;
            acc[q * 4 + 2] += e.z * v;
            acc[q * 4 + 3] += e.w * v;
        }
    }
#pragma unroll
    for (int k = 0; k < KEIG; k++) atomicAdd(&coeff[k * HDIM + h], acc[k]);
}

// x[n,h] = sum_k eig[n,k] * coeff[k,h]*exp(-lam_k*softplus(t_h)) -> feats[:,0:128]
__global__ void k_diffuse(const float* __restrict__ eig, const float* __restrict__ coeff,
                          const float* __restrict__ lam, const float* __restrict__ dt,
                          unsigned short* __restrict__ feats) {
    __shared__ float c2[KEIG * HDIM];
    int h = threadIdx.x;  // 128
    float tt = log1pf(expf(dt[h]));
#pragma unroll
    for (int j = 0; j < KEIG; j++) c2[j * HDIM + h] = coeff[j * HDIM + h] * expf(-lam[j] * tt);
    __syncthreads();
    int base = blockIdx.x * 64;
    for (int r = 0; r < 64; r++) {
        int n = base + r;
        if (n >= N_NODES) break;
        const float4* e4 = (const float4*)(eig + n * KEIG);
        float s = 0.f;
#pragma unroll
        for (int q = 0; q < 8; q++) {
            float4 e = e4[q];
            s += e.x * c2[(q * 4 + 0) * HDIM + h] + e.y * c2[(q * 4 + 1) * HDIM + h]
               + e.z * c2[(q * 4 + 2) * HDIM + h] + e.w * c2[(q * 4 + 3) * HDIM + h];
        }
        feats[(size_t)n * FEAT9 + h] = f2bf(s);
    }
}

// ---------------- CSR build ----------------
__global__ void k_hist(const int* __restrict__ dst, int* __restrict__ cnt) {
    int e = blockIdx.x * blockDim.x + threadIdx.x;
    if (e < N_EDGES) atomicAdd(&cnt[dst[e]], 1);
}

__global__ void k_scan_part(const int* __restrict__ cnt, int* __restrict__ bsum) {
    __shared__ int sm[256];
    int t = threadIdx.x, b = blockIdx.x;
    int base = b * 1024 + t * 4;
    int s = 0;
#pragma unroll
    for (int j = 0; j < 4; j++) { int i = base + j; if (i < N_NODES) s += cnt[i]; }
    sm[t] = s;
    __syncthreads();
    for (int d = 128; d > 0; d >>= 1) {
        if (t < d) sm[t] += sm[t + d];
        __syncthreads();
    }
    if (t == 0) bsum[b] = sm[0];
}

__global__ void k_scan_mid(const int* __restrict__ bsum, int* __restrict__ boff) {
    int t = threadIdx.x;  // 64
    int v = (t < 50) ? bsum[t] : 0;
    int x = v;
#pragma unroll
    for (int d = 1; d < 64; d <<= 1) {
        int y = __shfl_up(x, d, 64);
        if (t >= d) x += y;
    }
    boff[t] = x - v;  // exclusive
}

__global__ void k_scan_out(const int* __restrict__ cnt, const int* __restrict__ boff,
                           int* __restrict__ offsets, int* __restrict__ cursor) {
    __shared__ int sm[256];
    int t = threadIdx.x, b = blockIdx.x;
    int base = b * 1024 + t * 4;
    int c[4]; int ts = 0;
#pragma unroll
    for (int j = 0; j < 4; j++) { int i = base + j; c[j] = (i < N_NODES) ? cnt[i] : 0; ts += c[j]; }
    sm[t] = ts;
    __syncthreads();
    for (int d = 1; d < 256; d <<= 1) {
        int add = (t >= d) ? sm[t - d] : 0;
        __syncthreads();
        sm[t] += add;
        __syncthreads();
    }
    int run = boff[b] + sm[t] - ts;  // exclusive within-chip
#pragma unroll
    for (int j = 0; j < 4; j++) {
        int i = base + j;
        if (i < N_NODES) { offsets[i] = run; cursor[i] = run; run += c[j]; }
    }
    if (b == 0 && t == 0) offsets[N_NODES] = N_EDGES;
}

__global__ void k_bucket(const int* __restrict__ ei, const float* __restrict__ F,
                         int* __restrict__ cursor, int* __restrict__ ssrc,
                         float* __restrict__ sF) {
    int e = blockIdx.x * blockDim.x + threadIdx.x;
    if (e < N_EDGES) {
        int d = ei[N_EDGES + e];
        int p = atomicAdd(&cursor[d], 1);
        ssrc[p] = ei[e];
        sF[p] = F[e];
    }
}

// ---------------- per-node aggregation -> feats[:, 128:1152] ----------------
// 64 threads, 2 channels/thread via uint loads; edge loop unrolled x4 for MLP
__global__ __launch_bounds__(64) void k_agg(
    unsigned short* __restrict__ feats, const int* __restrict__ offsets,
    const int* __restrict__ ssrc, const float* __restrict__ sF,
    const float* __restrict__ degv, const float* __restrict__ Fdig) {
    int n = blockIdx.x;
    int t = threadIdx.x;  // 64, channels 2t and 2t+1
    int beg = offsets[n], end = offsets[n + 1];
    const unsigned* fx = (const unsigned*)feats;  // row pitch = 576 uints
    float s0 = 0.f, s1 = 0.f, w0 = 0.f, w1 = 0.f, f0 = 0.f, f1 = 0.f;
    float m0 = -3.4e38f, m1 = -3.4e38f, wS = 0.f;
    int e = beg;
    for (; e + 3 < end; e += 4) {
        int  sa = ssrc[e], sb = ssrc[e + 1], sc = ssrc[e + 2], sd = ssrc[e + 3];
        float Fa = sF[e], Fb = sF[e + 1], Fc = sF[e + 2], Fd = sF[e + 3];
        unsigned va = fx[(size_t)sa * 576 + t];
        unsigned vb = fx[(size_t)sb * 576 + t];
        unsigned vc = fx[(size_t)sc * 576 + t];
        unsigned vd = fx[(size_t)sd * 576 + t];
        float wa = fabsf(Fa), wb = fabsf(Fb), wc = fabsf(Fc), wd = fabsf(Fd);
        wS += wa + wb + wc + wd;
        float a0 = bf2f(va & 0xffff), a1 = bf2f(va >> 16);
        float b0 = bf2f(vb & 0xffff), b1 = bf2f(vb >> 16);
        float c0 = bf2f(vc & 0xffff), c1 = bf2f(vc >> 16);
        float d0 = bf2f(vd & 0xffff), d1 = bf2f(vd >> 16);
        s0 += a0 + b0 + c0 + d0;  s1 += a1 + b1 + c1 + d1;
        m0 = fmaxf(fmaxf(fmaxf(m0, a0), fmaxf(b0, c0)), d0);
        m1 = fmaxf(fmaxf(fmaxf(m1, a1), fmaxf(b1, c1)), d1);
        w0 += wa * a0 + wb * b0 + wc * c0 + wd * d0;
        w1 += wa * a1 + wb * b1 + wc * c1 + wd * d1;
        f0 += Fa * a0 + Fb * b0 + Fc * c0 + Fd * d0;
        f1 += Fa * a1 + Fb * b1 + Fc * c1 + Fd * d1;
    }
    for (; e < end; e++) {
        int sa = ssrc[e];
        float Fa = sF[e], wa = fabsf(Fa);
        unsigned va = fx[(size_t)sa * 576 + t];
        float a0 = bf2f(va & 0xffff), a1 = bf2f(va >> 16);
        s0 += a0; s1 += a1;
        m0 = fmaxf(m0, a0); m1 = fmaxf(m1, a1);
        w0 += wa * a0; w1 += wa * a1;
        f0 += Fa * a0; f1 += Fa * a1;
        wS += wa;
    }
    float dv = degv[n];
    float inv = 1.f / dv;
    float me0 = s0 * inv, me1 = s1 * inv;
    float mx0 = (end > beg) ? m0 : 0.f, mx1 = (end > beg) ? m1 : 0.f;
    float wi = 1.f / (wS + 1e-8f);
    float da0 = w0 * wi, da1 = w1 * wi;
    unsigned vx = fx[(size_t)n * 576 + t];
    float Fg = Fdig[n];
    float dd0 = f0 - Fg * bf2f(vx & 0xffff);
    float dd1 = f1 - Fg * bf2f(vx >> 16);
    float amp = log1pf(dv) / 2.5649493574615367f;  // log(13)
    unsigned* fr = (unsigned*)(feats + (size_t)n * FEAT9) + t;
    fr[64]  = pack2(me0, me1);
    fr[128] = pack2(mx0, mx1);
    fr[192] = pack2(da0, da1);
    fr[256] = pack2(dd0, dd1);
    fr[320] = pack2(me0 * amp, me1 * amp);
    fr[384] = pack2(mx0 * amp, mx1 * amp);
    fr[448] = pack2(da0 * amp, da1 * amp);
    fr[512] = pack2(dd0 * amp, dd1 * amp);
}

// ---------------- fused MFMA GEMM ----------------
// h=relu(feats@Wp+bp)*norm; out = x@WlA + h@WlB + bl + node_fts
// GEMM2a (x@WlA) fused into GEMM1's first 4 k-steps (same A fragments).
// A staging software-pipelined: step s+1 prefetched into regs before MFMAs.
__global__ __launch_bounds__(256, 4) void k_gemm(
    const unsigned short* __restrict__ feats, const unsigned short* __restrict__ Wswz,
    const unsigned short* __restrict__ WlA, const unsigned short* __restrict__ WlB,
    const float* __restrict__ b_post, const float* __restrict__ b_last,
    const float* __restrict__ norm_n, const float* __restrict__ node_fts,
    float* __restrict__ out) {
    __shared__ unsigned short As[64 * 40];  // 64 rows x 32k, +8 pad (2-way banks free)
    int tid = threadIdx.x;
    int wave = tid >> 6, lane = tid & 63;
    int m16 = lane & 15, quad = lane >> 4;
    int r0 = blockIdx.x * 64;

    // A staging map: thread -> (row, 16B chunk)
    int arow = tid >> 2, ac = tid & 3;
    int grow_st = r0 + arow;
    if (grow_st > N_NODES - 1) grow_st = N_NODES - 1;
    const unsigned short* gA = feats + (size_t)grow_st * FEAT9 + ac * 8;
    unsigned short* sA = As + arow * 40 + ac * 8;
    const unsigned short* aAddr = As + (wave * 16 + m16) * 40 + quad * 8;

    f4v acc1[8], acc2[8];
#pragma unroll
    for (int t = 0; t < 8; t++) { acc1[t] = (f4v)(0.f); acc2[t] = (f4v)(0.f); }

    s8v areg = *(const s8v*)gA;  // prefetch s=0
    for (int s = 0; s < 36; s++) {
        __syncthreads();
        *(s8v*)sA = areg;
        __syncthreads();
        if (s < 35) areg = *(const s8v*)(gA + (s + 1) * 32);  // prefetch next step
        s8v a = *(const s8v*)aAddr;
        if (s < 4) {  // GEMM2a: x @ W_last[0:128] shares these A fragments
            const s8v* bq = (const s8v*)WlA + (size_t)(s * 8) * 64 + lane;
#pragma unroll
            for (int nt = 0; nt < 8; nt++) {
                s8v b = bq[nt * 64];
                acc2[nt] = __builtin_amdgcn_mfma_f32_16x16x32_bf16(as_bf(a), as_bf(b), acc2[nt], 0, 0, 0);
            }
        }
        const s8v* bp = (const s8v*)Wswz + (size_t)(s * 8) * 64 + lane;
#pragma unroll
        for (int nt = 0; nt < 8; nt++) {
            s8v b = bp[nt * 64];
            acc1[nt] = __builtin_amdgcn_mfma_f32_16x16x32_bf16(as_bf(a), as_bf(b), acc1[nt], 0, 0, 0);
        }
    }

    // epilogue1: h = relu(acc1 + b_post[col]) * norm_n[row]   (in-place)
    int browbase = r0 + wave * 16 + quad * 4;
    float nrm[4];
#pragma unroll
    for (int r = 0; r < 4; r++) {
        int gr = browbase + r;
        if (gr > N_NODES - 1) gr = N_NODES - 1;
        nrm[r] = norm_n[gr];
    }
#pragma unroll
    for (int nt = 0; nt < 8; nt++) {
        float bb = b_post[nt * 16 + m16];
#pragma unroll
        for (int r = 0; r < 4; r++) {
            float v = acc1[nt][r] + bb;
            v = v > 0.f ? v : 0.f;
            acc1[nt][r] = v * nrm[r];
        }
    }

    // GEMM2b: h @ W_last[128:256], h staged 32 cols at a time from registers
    for (int s = 0; s < 4; s++) {
        __syncthreads();
#pragma unroll
        for (int half = 0; half < 2; half++) {
            int nt = s * 2 + half;
#pragma unroll
            for (int r = 0; r < 4; r++) {
                As[(wave * 16 + quad * 4 + r) * 40 + half * 16 + m16] = f2bf(acc1[nt][r]);
            }
        }
        __syncthreads();
        s8v a = *(const s8v*)aAddr;
        const s8v* bp = (const s8v*)WlB + (size_t)(s * 8) * 64 + lane;
#pragma unroll
        for (int nt = 0; nt < 8; nt++) {
            s8v b = bp[nt * 64];
            acc2[nt] = __builtin_amdgcn_mfma_f32_16x16x32_bf16(as_bf(a), as_bf(b), acc2[nt], 0, 0, 0);
        }
    }

    // epilogue2: out = acc2 + b_last + node_fts
#pragma unroll
    for (int nt = 0; nt < 8; nt++) {
        int col = nt * 16 + m16;
        float bl = b_last[col];
#pragma unroll
        for (int r = 0; r < 4; r++) {
            int gr = browbase + r;
            if (gr < N_NODES) {
                out[(size_t)gr * HDIM + col] = acc2[nt][r] + bl + node_fts[(size_t)gr * HDIM + col];
            }
        }
    }
}

extern "C" void kernel_launch(void* const* d_in, const int* in_sizes, int n_in,
                              void* d_out, int out_size, void* d_ws, size_t ws_size,
                              hipStream_t stream) {
    const float* node_fts = (const float*)d_in[0];
    const int*   eidx     = (const int*)d_in[2];
    const float* Fnorm    = (const float*)d_in[3];
    const float* Fdig     = (const float*)d_in[4];
    const float* degv     = (const float*)d_in[5];
    const float* lam      = (const float*)d_in[8];
    const float* eig      = (const float*)d_in[9];
    const float* norm_n   = (const float*)d_in[11];
    const float* dtimes   = (const float*)d_in[13];
    const float* Wp       = (const float*)d_in[14];
    const float* bp       = (const float*)d_in[15];
    const float* Wl       = (const float*)d_in[16];
    const float* bl       = (const float*)d_in[17];
    float* out = (float*)d_out;

    char* w = (char*)d_ws;
    size_t off = 0;
    auto carve = [&](size_t bytes) -> char* {
        char* p = w + off;
        off = (off + bytes + 255) & ~(size_t)255;
        return p;
    };
    unsigned short* feats = (unsigned short*)carve((size_t)N_NODES * FEAT9 * 2);
    unsigned short* Wswz  = (unsigned short*)carve((size_t)36 * 8 * 64 * 8 * 2);
    unsigned short* WlA   = (unsigned short*)carve((size_t)4 * 8 * 64 * 8 * 2);
    unsigned short* WlB   = (unsigned short*)carve((size_t)4 * 8 * 64 * 8 * 2);
    float* coeff  = (float*)carve(KEIG * HDIM * 4);
    int* cnt      = (int*)carve((size_t)N_NODES * 4);
    int* offsets  = (int*)carve(((size_t)N_NODES + 1) * 4);
    int* cursor   = (int*)carve((size_t)N_NODES * 4);
    int* ssrc     = (int*)carve((size_t)N_EDGES * 4);
    float* sF     = (float*)carve((size_t)N_EDGES * 4);
    int* bsum     = (int*)carve(64 * 4);
    int* boff     = (int*)carve(64 * 4);

    hipMemsetAsync(coeff, 0, KEIG * HDIM * 4, stream);
    hipMemsetAsync(cnt, 0, (size_t)N_NODES * 4, stream);

    k_prep<<<640, 256, 0, stream>>>(Wp, Wl, Wswz, WlA, WlB);
    k_coeff<<<(N_NODES + 31) / 32, 128, 0, stream>>>(node_fts, degv, eig, coeff);
    k_diffuse<<<(N_NODES + 63) / 64, 128, 0, stream>>>(eig, coeff, lam, dtimes, feats);
    k_hist<<<(N_EDGES + 255) / 256, 256, 0, stream>>>(eidx + N_EDGES, cnt);
    k_scan_part<<<50, 256, 0, stream>>>(cnt, bsum);
    k_scan_mid<<<1, 64, 0, stream>>>(bsum, boff);
    k_scan_out<<<50, 256, 0, stream>>>(cnt, boff, offsets, cursor);
    k_bucket<<<(N_EDGES + 255) / 256, 256, 0, stream>>>(eidx, Fnorm, cursor, ssrc, sF);
    k_agg<<<N_NODES, 64, 0, stream>>>(feats, offsets, ssrc, sF, degv, Fdig);
    k_gemm<<<(N_NODES + 63) / 64, 256, 0, stream>>>(feats, Wswz, WlA, WlB, bp, bl, norm_n,
                                                    node_fts, out);
}